// Round 5
// baseline (663.021 us; speedup 1.0000x reference)
//
#include <hip/hip_runtime.h>
#include <cstdint>
#include <cstddef>

#define E_DIM 1024
#define PD 64            // proj dim
#define NP 128           // 2*proj dim
#define B_DIM 8
#define S_DIM 2048
#define M_TOT (B_DIM * S_DIM)   // 16384

#define KH 512           // K per split-half
#define BM 64
#define BK 32
#define SP 36            // BK + 4 pad (36 floats = 144 B, 16B-aligned rows)
#define NCH (KH / BK)    // 16 chunks per half

// ---------------- K1: split-K GEMM partials (no bias) ----------------
// qkP[m][p] = sum_{k in half} A[m][k] * W[p][k];  A = context as (S*B,E), m = s*B+b
// 256 threads, per-thread 8 rows x 4 cols. Tiles [row][k] with +4 pad.
// All LDS traffic b128; scalar-extract idiom everywhere (no address-of float4 -> no scratch).
__global__ __launch_bounds__(256, 2) void gemm_qk(const float* __restrict__ A,
                                                  const float* __restrict__ W,
                                                  float* __restrict__ qk0,
                                                  float* __restrict__ qk1) {
    __shared__ float As[2][BM][SP];
    __shared__ float Bs[2][NP][SP];
    const int tid = threadIdx.x;
    const int kh  = blockIdx.x & 1;
    const int m0  = (blockIdx.x >> 1) * BM;
    const int k0  = kh * KH;
    const int tyr = tid >> 5;       // 0..7  -> rows tyr*8..+7
    const int txc = tid & 31;       // 0..31 -> cols txc*4..+3
    const int srow = tid >> 3;      // 0..31 staging row
    const int sk4 = (tid & 7) * 4;  // staging k offset (16B granule)

    float* qkP = kh ? qk1 : qk0;

    const float* aptr = A + (size_t)(m0 + srow) * E_DIM + k0 + sk4;
    const float* wptr = W + (size_t)srow * E_DIM + k0 + sk4;

    float acc[8][4];
#pragma unroll
    for (int i = 0; i < 8; ++i)
#pragma unroll
        for (int j = 0; j < 4; ++j) acc[i][j] = 0.f;

    // prologue: stage chunk 0 into buf 0
    float4 ra0 = *(const float4*)(aptr);
    float4 ra1 = *(const float4*)(aptr + 32 * E_DIM);
    float4 rw0 = *(const float4*)(wptr);
    float4 rw1 = *(const float4*)(wptr + 32 * E_DIM);
    float4 rw2 = *(const float4*)(wptr + 64 * E_DIM);
    float4 rw3 = *(const float4*)(wptr + 96 * E_DIM);
    *(float4*)&As[0][srow][sk4]       = ra0;
    *(float4*)&As[0][srow + 32][sk4]  = ra1;
    *(float4*)&Bs[0][srow][sk4]       = rw0;
    *(float4*)&Bs[0][srow + 32][sk4]  = rw1;
    *(float4*)&Bs[0][srow + 64][sk4]  = rw2;
    *(float4*)&Bs[0][srow + 96][sk4]  = rw3;

    for (int ch = 0; ch < NCH; ++ch) {
        const int buf = ch & 1;
        const int nb = buf ^ 1;
        __syncthreads();
        if (ch + 1 < NCH) {
            const int off = (ch + 1) * BK;
            ra0 = *(const float4*)(aptr + off);
            ra1 = *(const float4*)(aptr + off + 32 * E_DIM);
            rw0 = *(const float4*)(wptr + off);
            rw1 = *(const float4*)(wptr + off + 32 * E_DIM);
            rw2 = *(const float4*)(wptr + off + 64 * E_DIM);
            rw3 = *(const float4*)(wptr + off + 96 * E_DIM);
        }
#pragma unroll
        for (int g = 0; g < 8; ++g) {
            float a_[8][4];
#pragma unroll
            for (int i = 0; i < 8; ++i) {
                const float4 v = *(const float4*)&As[buf][tyr * 8 + i][g * 4];
                a_[i][0] = v.x; a_[i][1] = v.y; a_[i][2] = v.z; a_[i][3] = v.w;
            }
            float b_[4][4];
#pragma unroll
            for (int c = 0; c < 4; ++c) {
                const float4 v = *(const float4*)&Bs[buf][txc * 4 + c][g * 4];
                b_[c][0] = v.x; b_[c][1] = v.y; b_[c][2] = v.z; b_[c][3] = v.w;
            }
#pragma unroll
            for (int kk = 0; kk < 4; ++kk)
#pragma unroll
                for (int i = 0; i < 8; ++i)
#pragma unroll
                    for (int j = 0; j < 4; ++j)
                        acc[i][j] += a_[i][kk] * b_[j][kk];
        }
        if (ch + 1 < NCH) {
            *(float4*)&As[nb][srow][sk4]       = ra0;
            *(float4*)&As[nb][srow + 32][sk4]  = ra1;
            *(float4*)&Bs[nb][srow][sk4]       = rw0;
            *(float4*)&Bs[nb][srow + 32][sk4]  = rw1;
            *(float4*)&Bs[nb][srow + 64][sk4]  = rw2;
            *(float4*)&Bs[nb][srow + 96][sk4]  = rw3;
        }
    }

#pragma unroll
    for (int i = 0; i < 8; ++i) {
        float4 o;
        o.x = acc[i][0]; o.y = acc[i][1]; o.z = acc[i][2]; o.w = acc[i][3];
        *(float4*)&qkP[(size_t)(m0 + tyr * 8 + i) * NP + txc * 4] = o;
    }
}

// ---------------- K2: sum partials + bias, neighbor scores, 2-way softmax ----------------
__global__ __launch_bounds__(256) void neighbor_probs(const float* __restrict__ qk0,
                                                      const float* __restrict__ qk1,
                                                      const float* __restrict__ bias,
                                                      float* __restrict__ p0,
                                                      float* __restrict__ p1) {
    const int m = blockIdx.x * 4 + (threadIdx.x >> 6);  // position index m = s*B+b
    const int lane = threadIdx.x & 63;
    const int s = m >> 3;   // / B_DIM
    const int b = m & 7;    // % B_DIM

    const float bq = bias[lane];
    const float bk = bias[PD + lane];
    const float q = qk0[(size_t)m * NP + lane] + qk1[(size_t)m * NP + lane] + bq;
    float kn = 0.f, kp = 0.f;
    if (s < S_DIM - 1) {
        const size_t o = (size_t)(m + B_DIM) * NP + PD + lane;
        kn = qk0[o] + qk1[o] + bk;
    }
    if (s > 0) {
        const size_t o = (size_t)(m - B_DIM) * NP + PD + lane;
        kp = qk0[o] + qk1[o] + bk;
    }
    float f = q * kn;   // fwd partial: query[s] . key[s+1]
    float g = q * kp;   // bwd partial: query[s] . key[s-1]
#pragma unroll
    for (int off = 32; off; off >>= 1) {
        f += __shfl_xor(f, off);
        g += __shfl_xor(g, off);
    }
    if (lane == 0) {
        const float s0 = f * (1.f / (float)E_DIM);
        const float s1 = g * (1.f / (float)E_DIM);
        float P0, P1;
        if (s == S_DIM - 1) { P0 = 0.f; P1 = 1.f; }
        else if (s == 0)    { P0 = 1.f; P1 = 0.f; }
        else {
            const float mx = fmaxf(s0, s1);
            const float e0 = __expf(s0 - mx), e1 = __expf(s1 - mx);
            const float inv = 1.f / (e0 + e1);
            P0 = e0 * inv; P1 = e1 * inv;
        }
        p0[b * S_DIM + s] = P0;
        p1[b * S_DIM + s] = P1;
    }
}

// ---------------- K3: combine (flat roll), neighbor_attn out, log, exclusive scan ----------------
__global__ __launch_bounds__(256) void combine_scan(const float* __restrict__ p0,
                                                    const float* __restrict__ p1,
                                                    const float* __restrict__ prior,
                                                    float* __restrict__ out_na,
                                                    float* __restrict__ cs) {
    const int b = blockIdx.x;
    const int tid = threadIdx.x;
    __shared__ float sh[256];

    const int base = b * S_DIM + tid * 8;
    float incl[8];
    float run = 0.f;
#pragma unroll
    for (int u = 0; u < 8; ++u) {
        const int fidx = base + u;
        int nf = fidx + 1;
        if (nf == B_DIM * S_DIM) nf = 0;   // torch .roll on flattened tensor wraps globally
        const float P0 = p0[fidx];
        const float sp = p1[nf];
        const float pr = prior[fidx];
        const float na = pr + (1.f - pr) * sqrtf(P0 * sp + 1e-6f);
        out_na[fidx] = na;
        run += __logf(na);
        incl[u] = run;
    }
    sh[tid] = run;
    __syncthreads();
    for (int off = 1; off < 256; off <<= 1) {
        float v = sh[tid];
        if (tid >= off) v += sh[tid - off];
        __syncthreads();
        sh[tid] = v;
        __syncthreads();
    }
    const float offset = (tid > 0) ? sh[tid - 1] : 0.f;
#pragma unroll
    for (int u = 0; u < 8; ++u) {
        cs[base + u] = offset + ((u > 0) ? incl[u - 1] : 0.f);  // exclusive prefix
    }
}

// ---------------- K4: big output C[b,i,j] = exp(sign*(cs[j]-cs[i])), 0 on diag ----------------
__global__ __launch_bounds__(256) void big_out(const float* __restrict__ cs,
                                               float* __restrict__ out) {
    const int bi = blockIdx.x;          // b*S + i
    const int b = bi >> 11;             // / S_DIM
    const int i = bi & (S_DIM - 1);
    const float ci = cs[b * S_DIM + i];
    const float* crow = cs + (size_t)b * S_DIM;
    float* orow = out + (size_t)bi * S_DIM;
    const int j0 = threadIdx.x * 8;
#pragma unroll
    for (int h = 0; h < 2; ++h) {
        const int j = j0 + h * 4;
        const float4 cj = *(const float4*)&crow[j];
        float4 o;
        {
            const int jj = j + 0; const float m = (jj > i) ? (cj.x - ci) : (ci - cj.x);
            o.x = (jj == i) ? 0.f : __expf(m);
        }
        {
            const int jj = j + 1; const float m = (jj > i) ? (cj.y - ci) : (ci - cj.y);
            o.y = (jj == i) ? 0.f : __expf(m);
        }
        {
            const int jj = j + 2; const float m = (jj > i) ? (cj.z - ci) : (ci - cj.z);
            o.z = (jj == i) ? 0.f : __expf(m);
        }
        {
            const int jj = j + 3; const float m = (jj > i) ? (cj.w - ci) : (ci - cj.w);
            o.w = (jj == i) ? 0.f : __expf(m);
        }
        *(float4*)&orow[j] = o;
    }
}

extern "C" void kernel_launch(void* const* d_in, const int* in_sizes, int n_in,
                              void* d_out, int out_size, void* d_ws, size_t ws_size,
                              hipStream_t stream) {
    const float* context = (const float*)d_in[0];   // (S,B,E) fp32
    const float* prior   = (const float*)d_in[1];   // (B,S) fp32
    const float* W       = (const float*)d_in[2];   // (128,1024) fp32
    const float* bias    = (const float*)d_in[3];   // (128,) fp32
    float* out = (float*)d_out;

    float* qk0 = (float*)d_ws;                         // 16384*128 floats
    float* p0  = qk0 + (size_t)M_TOT * NP;             // 16384 floats
    float* p1  = p0 + M_TOT;                           // 16384 floats
    float* cs  = p1 + M_TOT;                           // 16384 floats
    // second partial lives in d_out's C-region; K4 overwrites it afterwards
    float* qk1 = out;
    float* na_out = out + (size_t)B_DIM * S_DIM * S_DIM;  // second output

    gemm_qk<<<(M_TOT / BM) * 2, 256, 0, stream>>>(context, W, qk0, qk1);
    neighbor_probs<<<M_TOT / 4, 256, 0, stream>>>(qk0, qk1, bias, p0, p1);
    combine_scan<<<B_DIM, 256, 0, stream>>>(p0, p1, prior, na_out, cs);
    big_out<<<M_TOT, 256, 0, stream>>>(cs, out);
}

// Round 6
// 107.243 us; speedup vs baseline: 6.1824x; 6.1824x over previous
//
#include <hip/hip_runtime.h>
#include <cstdint>
#include <cstddef>

#define E_DIM 1024
#define PD 64            // proj dim
#define NP 128           // 2*proj dim
#define B_DIM 8
#define S_DIM 2048
#define M_TOT (B_DIM * S_DIM)   // 16384

#define KH 512           // K per split-half
#define BM 64
#define BK 32
#define NCH (KH / BK)    // 16 chunks per half

__device__ __forceinline__ void gload16(const float* g, float* l) {
    __builtin_amdgcn_global_load_lds(
        (const __attribute__((address_space(1))) unsigned int*)g,
        (__attribute__((address_space(3))) unsigned int*)(uintptr_t)l,
        16, 0, 0);
}

// ---------------- K1: split-K GEMM partials (no bias) ----------------
// qkP[m][p] = sum_{k in half} A[m][k]*W[p][k];  A = context as (S*B,E), m = s*B+b.
// 256 thr, per-thread 8 rows x 4 cols. ALL staging via global_load_lds (no staging
// registers live across compute -> no spill). LDS linear [row][32] as gload requires.
// B data granule-swizzled at the SOURCE (m173): slot (p, gp) holds logical granule
// gp ^ ((p>>2)&7); reads use gp = g ^ (txc&7) -> 8 bank-groups, structural floor.
// A reads are 2-way broadcast (free).
__global__ __launch_bounds__(256, 2) void gemm_qk(const float* __restrict__ A,
                                                  const float* __restrict__ W,
                                                  float* __restrict__ qk0,
                                                  float* __restrict__ qk1) {
    __shared__ float As[2][BM][BK];   // [64][32] linear
    __shared__ float Bs[2][NP][BK];   // [128][32] linear, data pre-swizzled
    const int tid = threadIdx.x;
    const int kh  = blockIdx.x & 1;
    const int m0  = (blockIdx.x >> 1) * BM;
    const int k0  = kh * KH;
    const int w   = __builtin_amdgcn_readfirstlane(tid >> 6);  // wave id (uniform)
    const int ln  = tid & 63;
    const int tyr = tid >> 5;       // 0..7  -> rows tyr*8..+7
    const int txc = tid & 31;       // 0..31 -> cols txc*4..+3

    float* qkP = kh ? qk1 : qk0;

    // A staging: issue j (0..1) covers rows w*16 + j*8 + (ln>>3), granule ln&7 (no swizzle)
    const float* aSrc0 = A + (size_t)(m0 + w * 16 + (ln >> 3)) * E_DIM + k0 + ((ln & 7) << 2);
    const float* aSrc1 = aSrc0 + 8 * E_DIM;
    // B staging: issue j (0..3) covers p = w*32 + j*8 + (ln>>3);
    // source granule = (ln&7) ^ ((p>>2)&7)
    const int prow0 = w * 32 + (ln >> 3);
    const float* bSrc0 = W + (size_t)(prow0     ) * E_DIM + k0 + ((((ln & 7) ^ (((prow0     ) >> 2) & 7))) << 2);
    const float* bSrc1 = W + (size_t)(prow0 +  8) * E_DIM + k0 + ((((ln & 7) ^ (((prow0 +  8) >> 2) & 7))) << 2);
    const float* bSrc2 = W + (size_t)(prow0 + 16) * E_DIM + k0 + ((((ln & 7) ^ (((prow0 + 16) >> 2) & 7))) << 2);
    const float* bSrc3 = W + (size_t)(prow0 + 24) * E_DIM + k0 + ((((ln & 7) ^ (((prow0 + 24) >> 2) & 7))) << 2);

    float acc[8][4];
#pragma unroll
    for (int i = 0; i < 8; ++i)
#pragma unroll
        for (int j = 0; j < 4; ++j) acc[i][j] = 0.f;

    // prologue: stage chunk 0 into buf 0
    gload16(aSrc0, &As[0][w * 16][0]);
    gload16(aSrc1, &As[0][w * 16 + 8][0]);
    gload16(bSrc0, &Bs[0][w * 32][0]);
    gload16(bSrc1, &Bs[0][w * 32 + 8][0]);
    gload16(bSrc2, &Bs[0][w * 32 + 16][0]);
    gload16(bSrc3, &Bs[0][w * 32 + 24][0]);

    const int bksw = txc & 7;   // B read granule xor key (same for all 4 cols of this thread)

    for (int ch = 0; ch < NCH; ++ch) {
        const int buf = ch & 1;
        __syncthreads();   // drains this wave's gloads (vmcnt0) + block barrier
        if (ch + 1 < NCH) {
            const int nb = buf ^ 1;
            const int off = (ch + 1) * BK;
            gload16(aSrc0 + off, &As[nb][w * 16][0]);
            gload16(aSrc1 + off, &As[nb][w * 16 + 8][0]);
            gload16(bSrc0 + off, &Bs[nb][w * 32][0]);
            gload16(bSrc1 + off, &Bs[nb][w * 32 + 8][0]);
            gload16(bSrc2 + off, &Bs[nb][w * 32 + 16][0]);
            gload16(bSrc3 + off, &Bs[nb][w * 32 + 24][0]);
        }
#pragma unroll
        for (int g = 0; g < 8; ++g) {
            const int gp = ((g ^ bksw) & 7) << 2;
            const float4 b0 = *(const float4*)&Bs[buf][txc * 4 + 0][gp];
            const float4 b1 = *(const float4*)&Bs[buf][txc * 4 + 1][gp];
            const float4 b2 = *(const float4*)&Bs[buf][txc * 4 + 2][gp];
            const float4 b3 = *(const float4*)&Bs[buf][txc * 4 + 3][gp];
#pragma unroll
            for (int i = 0; i < 8; ++i) {
                const float4 a = *(const float4*)&As[buf][tyr * 8 + i][g << 2];
                acc[i][0] += a.x * b0.x; acc[i][0] += a.y * b0.y;
                acc[i][0] += a.z * b0.z; acc[i][0] += a.w * b0.w;
                acc[i][1] += a.x * b1.x; acc[i][1] += a.y * b1.y;
                acc[i][1] += a.z * b1.z; acc[i][1] += a.w * b1.w;
                acc[i][2] += a.x * b2.x; acc[i][2] += a.y * b2.y;
                acc[i][2] += a.z * b2.z; acc[i][2] += a.w * b2.w;
                acc[i][3] += a.x * b3.x; acc[i][3] += a.y * b3.y;
                acc[i][3] += a.z * b3.z; acc[i][3] += a.w * b3.w;
            }
        }
    }

#pragma unroll
    for (int i = 0; i < 8; ++i) {
        float4 o;
        o.x = acc[i][0]; o.y = acc[i][1]; o.z = acc[i][2]; o.w = acc[i][3];
        *(float4*)&qkP[(size_t)(m0 + tyr * 8 + i) * NP + txc * 4] = o;
    }
}

// ---------------- K2: sum partials + bias, neighbor scores, 2-way softmax ----------------
__global__ __launch_bounds__(256) void neighbor_probs(const float* __restrict__ qk0,
                                                      const float* __restrict__ qk1,
                                                      const float* __restrict__ bias,
                                                      float* __restrict__ p0,
                                                      float* __restrict__ p1) {
    const int m = blockIdx.x * 4 + (threadIdx.x >> 6);  // position index m = s*B+b
    const int lane = threadIdx.x & 63;
    const int s = m >> 3;   // / B_DIM
    const int b = m & 7;    // % B_DIM

    const float bq = bias[lane];
    const float bk = bias[PD + lane];
    const float q = qk0[(size_t)m * NP + lane] + qk1[(size_t)m * NP + lane] + bq;
    float kn = 0.f, kp = 0.f;
    if (s < S_DIM - 1) {
        const size_t o = (size_t)(m + B_DIM) * NP + PD + lane;
        kn = qk0[o] + qk1[o] + bk;
    }
    if (s > 0) {
        const size_t o = (size_t)(m - B_DIM) * NP + PD + lane;
        kp = qk0[o] + qk1[o] + bk;
    }
    float f = q * kn;   // fwd partial: query[s] . key[s+1]
    float g = q * kp;   // bwd partial: query[s] . key[s-1]
#pragma unroll
    for (int off = 32; off; off >>= 1) {
        f += __shfl_xor(f, off);
        g += __shfl_xor(g, off);
    }
    if (lane == 0) {
        const float s0 = f * (1.f / (float)E_DIM);
        const float s1 = g * (1.f / (float)E_DIM);
        float P0, P1;
        if (s == S_DIM - 1) { P0 = 0.f; P1 = 1.f; }
        else if (s == 0)    { P0 = 1.f; P1 = 0.f; }
        else {
            const float mx = fmaxf(s0, s1);
            const float e0 = __expf(s0 - mx), e1 = __expf(s1 - mx);
            const float inv = 1.f / (e0 + e1);
            P0 = e0 * inv; P1 = e1 * inv;
        }
        p0[b * S_DIM + s] = P0;
        p1[b * S_DIM + s] = P1;
    }
}

// ---------------- K3: combine (flat roll), neighbor_attn out, log, exclusive scan ----------------
__global__ __launch_bounds__(256) void combine_scan(const float* __restrict__ p0,
                                                    const float* __restrict__ p1,
                                                    const float* __restrict__ prior,
                                                    float* __restrict__ out_na,
                                                    float* __restrict__ cs) {
    const int b = blockIdx.x;
    const int tid = threadIdx.x;
    __shared__ float sh[256];

    const int base = b * S_DIM + tid * 8;
    float incl[8];
    float run = 0.f;
#pragma unroll
    for (int u = 0; u < 8; ++u) {
        const int fidx = base + u;
        int nf = fidx + 1;
        if (nf == B_DIM * S_DIM) nf = 0;   // torch .roll on flattened tensor wraps globally
        const float P0 = p0[fidx];
        const float sp = p1[nf];
        const float pr = prior[fidx];
        const float na = pr + (1.f - pr) * sqrtf(P0 * sp + 1e-6f);
        out_na[fidx] = na;
        run += __logf(na);
        incl[u] = run;
    }
    sh[tid] = run;
    __syncthreads();
    for (int off = 1; off < 256; off <<= 1) {
        float v = sh[tid];
        if (tid >= off) v += sh[tid - off];
        __syncthreads();
        sh[tid] = v;
        __syncthreads();
    }
    const float offset = (tid > 0) ? sh[tid - 1] : 0.f;
#pragma unroll
    for (int u = 0; u < 8; ++u) {
        cs[base + u] = offset + ((u > 0) ? incl[u - 1] : 0.f);  // exclusive prefix
    }
}

// ---------------- K4: big output C[b,i,j] = exp(sign*(cs[j]-cs[i])), 0 on diag ----------------
__global__ __launch_bounds__(256) void big_out(const float* __restrict__ cs,
                                               float* __restrict__ out) {
    const int bi = blockIdx.x;          // b*S + i
    const int b = bi >> 11;             // / S_DIM
    const int i = bi & (S_DIM - 1);
    const float ci = cs[b * S_DIM + i];
    const float* crow = cs + (size_t)b * S_DIM;
    float* orow = out + (size_t)bi * S_DIM;
    const int j0 = threadIdx.x * 8;
#pragma unroll
    for (int h = 0; h < 2; ++h) {
        const int j = j0 + h * 4;
        const float4 cj = *(const float4*)&crow[j];
        float4 o;
        {
            const int jj = j + 0; const float m = (jj > i) ? (cj.x - ci) : (ci - cj.x);
            o.x = (jj == i) ? 0.f : __expf(m);
        }
        {
            const int jj = j + 1; const float m = (jj > i) ? (cj.y - ci) : (ci - cj.y);
            o.y = (jj == i) ? 0.f : __expf(m);
        }
        {
            const int jj = j + 2; const float m = (jj > i) ? (cj.z - ci) : (ci - cj.z);
            o.z = (jj == i) ? 0.f : __expf(m);
        }
        {
            const int jj = j + 3; const float m = (jj > i) ? (cj.w - ci) : (ci - cj.w);
            o.w = (jj == i) ? 0.f : __expf(m);
        }
        *(float4*)&orow[j] = o;
    }
}

extern "C" void kernel_launch(void* const* d_in, const int* in_sizes, int n_in,
                              void* d_out, int out_size, void* d_ws, size_t ws_size,
                              hipStream_t stream) {
    const float* context = (const float*)d_in[0];   // (S,B,E) fp32
    const float* prior   = (const float*)d_in[1];   // (B,S) fp32
    const float* W       = (const float*)d_in[2];   // (128,1024) fp32
    const float* bias    = (const float*)d_in[3];   // (128,) fp32
    float* out = (float*)d_out;

    float* qk0 = (float*)d_ws;                         // 16384*128 floats
    float* p0  = qk0 + (size_t)M_TOT * NP;             // 16384 floats
    float* p1  = p0 + M_TOT;                           // 16384 floats
    float* cs  = p1 + M_TOT;                           // 16384 floats
    // second partial lives in d_out's C-region; K4 overwrites it afterwards
    float* qk1 = out;
    float* na_out = out + (size_t)B_DIM * S_DIM * S_DIM;  // second output

    gemm_qk<<<(M_TOT / BM) * 2, 256, 0, stream>>>(context, W, qk0, qk1);
    neighbor_probs<<<M_TOT / 4, 256, 0, stream>>>(qk0, qk1, bias, p0, p1);
    combine_scan<<<B_DIM, 256, 0, stream>>>(p0, p1, prior, na_out, cs);
    big_out<<<M_TOT, 256, 0, stream>>>(cs, out);
}